// Round 1
// baseline (272.565 us; speedup 1.0000x reference)
//
#include <hip/hip_runtime.h>

// NNGLS: y_decor, o_decor, o  for N=200000 nodes, M=20 neighbors, MLP 64->256->1.
//
// K1 (mlp_kernel): o = relu(x@w1+b1)@w2+b2, fp32 VALU, w1 staged in LDS,
//                  2 nodes/thread so one LDS b128 broadcast feeds 32 fmas.
// K2 (solve_kernel): bordered 21x21 covariance per node, upper-packed in
//                  231 registers (fully unrolled), 20 steps of symmetric
//                  Gaussian elimination applied to rhs [y_nbr;y_i],[o_nbr;o_i].
//                  Last pivot == f_i, last rhs entries == decorrelation
//                  numerators  =>  no b_i materialization, no back-subst.

#define MM   20
#define PP   64
#define HH   256
#define EPSF 1e-12f

// packed upper-triangle index for 21x21, r <= c
#define UT(r, c) ((r)*21 - ((r)*((r)-1))/2 + ((c)-(r)))

__global__ __launch_bounds__(256, 2)
void mlp_kernel(const float* __restrict__ x,
                const float* __restrict__ w1,
                const float* __restrict__ b1,
                const float* __restrict__ w2,
                const float* __restrict__ b2,
                float* __restrict__ o_out, int n)
{
    __shared__ float sw1[PP * HH];          // 64 KB
    const int t = threadIdx.x;

    // cooperative stage of w1: 16384 floats / 256 threads = 16 float4 each
    #pragma unroll
    for (int k = 0; k < 16; ++k) {
        const int e = (k * 256 + t) * 4;
        *(float4*)&sw1[e] = *(const float4*)&w1[e];
    }
    __syncthreads();

    const int base  = blockIdx.x * 512;
    const int node0 = base + t;
    const int node1 = base + t + 256;
    const bool ok0 = node0 < n;
    const bool ok1 = node1 < n;

    float xr0[PP], xr1[PP];
    if (ok0) {
        const float4* x4 = (const float4*)(x + (size_t)node0 * PP);
        #pragma unroll
        for (int k = 0; k < PP / 4; ++k) {
            float4 v = x4[k];
            xr0[4*k] = v.x; xr0[4*k+1] = v.y; xr0[4*k+2] = v.z; xr0[4*k+3] = v.w;
        }
    }
    if (ok1) {
        const float4* x4 = (const float4*)(x + (size_t)node1 * PP);
        #pragma unroll
        for (int k = 0; k < PP / 4; ++k) {
            float4 v = x4[k];
            xr1[4*k] = v.x; xr1[4*k+1] = v.y; xr1[4*k+2] = v.z; xr1[4*k+3] = v.w;
        }
    }

    float oacc0 = b2[0];
    float oacc1 = oacc0;

    for (int hb = 0; hb < HH / 16; ++hb) {
        const int hoff = hb * 16;
        float acc0[16], acc1[16];
        #pragma unroll
        for (int j = 0; j < 16; ++j) {
            float bj = b1[hoff + j];        // uniform -> scalar load
            acc0[j] = bj; acc1[j] = bj;
        }
        #pragma unroll
        for (int p = 0; p < PP; ++p) {
            const float* wrow = &sw1[p * HH + hoff];
            float4 wa = *(const float4*)(wrow);
            float4 wb = *(const float4*)(wrow + 4);
            float4 wc = *(const float4*)(wrow + 8);
            float4 wd = *(const float4*)(wrow + 12);
            float w[16] = { wa.x, wa.y, wa.z, wa.w,
                            wb.x, wb.y, wb.z, wb.w,
                            wc.x, wc.y, wc.z, wc.w,
                            wd.x, wd.y, wd.z, wd.w };
            const float xp0 = xr0[p];
            const float xp1 = xr1[p];
            #pragma unroll
            for (int j = 0; j < 16; ++j) {
                acc0[j] = fmaf(xp0, w[j], acc0[j]);
                acc1[j] = fmaf(xp1, w[j], acc1[j]);
            }
        }
        #pragma unroll
        for (int j = 0; j < 16; ++j) {
            const float w2j = w2[hoff + j];   // uniform
            oacc0 = fmaf(fmaxf(acc0[j], 0.0f), w2j, oacc0);
            oacc1 = fmaf(fmaxf(acc1[j], 0.0f), w2j, oacc1);
        }
    }
    if (ok0) o_out[node0] = oacc0;
    if (ok1) o_out[node1] = oacc1;
}

__global__ __launch_bounds__(64, 1)
void solve_kernel(const float* __restrict__ pos,
                  const float* __restrict__ y,
                  const int*   __restrict__ nbr,
                  const float* __restrict__ theta,
                  const float* __restrict__ o_in,
                  float* __restrict__ yd,
                  float* __restrict__ od, int n)
{
    const int i = blockIdx.x * 64 + threadIdx.x;
    if (i >= n) return;

    const float sigma_sq = theta[0];
    const float phi      = theta[1];
    const float tau      = theta[2];
    const float tau_sq   = tau * sigma_sq;

    const float L2E = 1.44269504088896340736f;
    const float c1  = -phi * L2E;                         // exp(-phi*d) = exp2(c1*d)
    const float c0  = __builtin_amdgcn_logf(sigma_sq);    // log2(sigma_sq): folds sigma^2 into exp2

    // --- gather neighbor indices (80B row, 16B-aligned) ---
    int idx[MM];
    const int4* nb4 = (const int4*)(nbr + (size_t)i * MM);
    #pragma unroll
    for (int k = 0; k < MM / 4; ++k) {
        int4 v = nb4[k];
        idx[4*k] = v.x; idx[4*k+1] = v.y; idx[4*k+2] = v.z; idx[4*k+3] = v.w;
    }

    // --- gather positions: neighbors 0..19, self at 20 ---
    float px[21], py[21];
    const float2* pos2 = (const float2*)pos;
    #pragma unroll
    for (int j = 0; j < MM; ++j) {
        float2 p = pos2[idx[j]];
        px[j] = p.x; py[j] = p.y;
    }
    {
        float2 p = pos2[i];
        px[20] = p.x; py[20] = p.y;
    }

    // --- build bordered 21x21 covariance, upper-packed in registers ---
    // diag (j<20): sigma^2*exp(-phi*sqrt(EPS)) + tau*sigma^2 ; corner: sigma^2 + tau
    const float sqrtEPS = __builtin_amdgcn_sqrtf(EPSF);
    const float diagA   = __builtin_amdgcn_exp2f(fmaf(sqrtEPS, c1, c0)) + tau_sq;

    float a[231];
    #pragma unroll
    for (int r = 0; r < 21; ++r) {
        #pragma unroll
        for (int c = r; c < 21; ++c) {
            if (r == c) {
                a[UT(r, c)] = (r == 20) ? (sigma_sq + tau) : diagA;
            } else {
                float dx = px[r] - px[c];
                float dy = py[r] - py[c];
                float d2 = fmaf(dx, dx, fmaf(dy, dy, EPSF));
                float d  = __builtin_amdgcn_sqrtf(d2);
                a[UT(r, c)] = __builtin_amdgcn_exp2f(fmaf(d, c1, c0));
            }
        }
    }

    // --- gather rhs (after build to lower register peak) ---
    float yv[21], ov[21];
    #pragma unroll
    for (int j = 0; j < MM; ++j) {
        yv[j] = y[idx[j]];
        ov[j] = o_in[idx[j]];
    }
    yv[20] = y[i];
    ov[20] = o_in[i];

    // --- 20 steps of symmetric Gaussian elimination (SPD: no pivoting) ---
    #pragma unroll
    for (int k = 0; k < 20; ++k) {
        const float p  = a[UT(k, k)];
        float rp = __builtin_amdgcn_rcpf(p);
        rp = rp * (2.0f - p * rp);                 // Newton: ~full fp32 precision
        #pragma unroll
        for (int r = k + 1; r < 21; ++r) {
            const float m = a[UT(k, r)] * rp;      // multiplier (symmetry: A[r][k]==A[k][r])
            #pragma unroll
            for (int c = r; c < 21; ++c)
                a[UT(r, c)] = fmaf(-m, a[UT(k, c)], a[UT(r, c)]);
            yv[r] = fmaf(-m, yv[k], yv[r]);
            ov[r] = fmaf(-m, ov[k], ov[r]);
        }
    }

    const float f = a[UT(20, 20)];                 // Schur complement == f_i
    float is = __builtin_amdgcn_rsqf(f);
    is = is * fmaf(-0.5f * f * is, is, 1.5f);      // Newton for rsqrt
    yd[i] = yv[20] * is;
    od[i] = ov[20] * is;
}

extern "C" void kernel_launch(void* const* d_in, const int* in_sizes, int n_in,
                              void* d_out, int out_size, void* d_ws, size_t ws_size,
                              hipStream_t stream)
{
    const float* x     = (const float*)d_in[0];
    const float* pos   = (const float*)d_in[1];
    const float* y     = (const float*)d_in[2];
    const int*   nbr   = (const int*)  d_in[3];
    const float* theta = (const float*)d_in[4];
    const float* w1    = (const float*)d_in[5];
    const float* b1    = (const float*)d_in[6];
    const float* w2    = (const float*)d_in[7];
    const float* b2    = (const float*)d_in[8];

    const int n = in_sizes[2];                 // N (y is [N])
    float* out = (float*)d_out;
    float* yd = out;                           // y_decor
    float* od = out + (size_t)n;               // o_decor
    float* oo = out + 2 * (size_t)n;           // o  (also K2's gather source)

    mlp_kernel<<<(n + 511) / 512, 256, 0, stream>>>(x, w1, b1, w2, b2, oo, n);
    solve_kernel<<<(n + 63) / 64, 64, 0, stream>>>(pos, y, nbr, theta, oo, yd, od, n);
}

// Round 2
// 234.710 us; speedup vs baseline: 1.1613x; 1.1613x over previous
//
#include <hip/hip_runtime.h>

// NNGLS: y_decor, o_decor, o for N=200000, M=20, MLP 64->256->1.
//
// K1 (mlp_mfma_kernel): split-bf16 MFMA GEMM (x=xh+xl, w1=wh+wl; 3 passes
//     ah*bh + al*bh + ah*bl => ~fp32 accuracy). Wave owns 64 nodes (4 M-tiles
//     of mfma_f32_16x16x32_bf16); w1 staged frag-ordered in LDS (hi+lo, 64KB);
//     layer2 (relu->dot w2) fused via per-lane partials + shfl_xor reduction.
// K2 (solve_kernel): bordered 21x21 covariance per thread in 231 registers.
//     Build fully unrolled; elimination is a REAL 20-iter loop (small code,
//     fits 32KB I$): switch copies pivot row k into fixed regs pr[], then a
//     masked full-triangle rank-1 update with compile-time register indices.

#define MM   20
#define PP   64
#define HH   256
#define EPSF 1e-12f
#define UT(r, c) ((r)*21 - ((r)*((r)-1))/2 + ((c)-(r)))

typedef __attribute__((ext_vector_type(8))) short bf16x8;
typedef __attribute__((ext_vector_type(4))) float f32x4;

static __device__ __forceinline__ unsigned short f2bf(float f) {
    unsigned int u = __builtin_bit_cast(unsigned int, f);
    u += 0x7fffu + ((u >> 16) & 1u);          // RNE
    return (unsigned short)(u >> 16);
}
static __device__ __forceinline__ float bf2f(unsigned short h) {
    unsigned int u = ((unsigned int)h) << 16;
    return __builtin_bit_cast(float, u);
}

__global__ __launch_bounds__(256, 2)
void mlp_mfma_kernel(const float* __restrict__ x,
                     const float* __restrict__ w1,
                     const float* __restrict__ b1,
                     const float* __restrict__ w2,
                     const float* __restrict__ b2,
                     float* __restrict__ o_out, int n)
{
    __shared__ __align__(16) short swh[PP * HH];   // 32 KB  w1 hi, frag order
    __shared__ __align__(16) short swl[PP * HH];   // 32 KB  w1 lo
    const int tid = threadIdx.x;

    // ---- stage w1 -> frag-ordered bf16 hi/lo ----
    // frag index for (k, col): t=col>>4, nn=col&15, s=k>>5, q=(k>>3)&3, j=k&7
    // flat = ((((t*2+s)*4+q)*16)+nn)*8 + j
    {
        const int col = tid;                       // 256 cols, one per thread
        const int t = col >> 4, nn = col & 15;
        #pragma unroll
        for (int g = 0; g < 8; ++g) {              // k = g*8 + u
            const int s = g >> 2, q = g & 3;
            bf16x8 hv, lv;
            #pragma unroll
            for (int u = 0; u < 8; ++u) {
                float v = w1[(g * 8 + u) * HH + col];
                unsigned short h = f2bf(v);
                hv[u] = (short)h;
                lv[u] = (short)f2bf(v - bf2f(h));
            }
            const int base = ((((t * 2 + s) * 4 + q) * 16) + nn) * 8;
            *(bf16x8*)&swh[base] = hv;
            *(bf16x8*)&swl[base] = lv;
        }
    }
    __syncthreads();

    const int lane = tid & 63;
    const int wv   = tid >> 6;
    const int nn   = lane & 15;      // A-row (node) / B-col (hidden) / C-col
    const int q    = lane >> 4;      // quad
    const int wb   = blockIdx.x * 256 + wv * 64;   // first node of this wave

    // per-lane slices of b1 / w2 (col = t*16 + nn)
    float w2v[16], b1v[16];
    #pragma unroll
    for (int t = 0; t < 16; ++t) {
        w2v[t] = w2[t * 16 + nn];
        b1v[t] = b1[t * 16 + nn];
    }

    // ---- A fragments: 4 M-tiles x 2 k-steps, split hi/lo ----
    bf16x8 ah[4][2], al[4][2];
    #pragma unroll
    for (int mt = 0; mt < 4; ++mt) {
        const int row = wb + mt * 16 + nn;
        #pragma unroll
        for (int s = 0; s < 2; ++s) {
            float v[8];
            if (row < n) {
                const float* xp = x + (size_t)row * PP + s * 32 + q * 8;
                float4 va = *(const float4*)(xp);
                float4 vb = *(const float4*)(xp + 4);
                v[0]=va.x; v[1]=va.y; v[2]=va.z; v[3]=va.w;
                v[4]=vb.x; v[5]=vb.y; v[6]=vb.z; v[7]=vb.w;
            } else {
                #pragma unroll
                for (int u = 0; u < 8; ++u) v[u] = 0.0f;
            }
            bf16x8 h, l;
            #pragma unroll
            for (int u = 0; u < 8; ++u) {
                unsigned short hb = f2bf(v[u]);
                h[u] = (short)hb;
                l[u] = (short)f2bf(v[u] - bf2f(hb));
            }
            ah[mt][s] = h;
            al[mt][s] = l;
        }
    }

    float part[4][4];
    #pragma unroll
    for (int mt = 0; mt < 4; ++mt)
        #pragma unroll
        for (int r = 0; r < 4; ++r) part[mt][r] = 0.0f;

    // ---- hidden tiles: MFMA + fused bias/relu/dot ----
    for (int t = 0; t < 16; ++t) {
        f32x4 acc[4];
        #pragma unroll
        for (int mt = 0; mt < 4; ++mt) acc[mt] = (f32x4)(0.0f);
        #pragma unroll
        for (int s = 0; s < 2; ++s) {
            const int fb = ((((t * 2 + s) * 4 + q) * 16) + nn) * 8;
            bf16x8 bh = *(const bf16x8*)&swh[fb];
            bf16x8 bl = *(const bf16x8*)&swl[fb];
            #pragma unroll
            for (int mt = 0; mt < 4; ++mt) {
                acc[mt] = __builtin_amdgcn_mfma_f32_16x16x32_bf16(ah[mt][s], bh, acc[mt], 0, 0, 0);
                acc[mt] = __builtin_amdgcn_mfma_f32_16x16x32_bf16(al[mt][s], bh, acc[mt], 0, 0, 0);
                acc[mt] = __builtin_amdgcn_mfma_f32_16x16x32_bf16(ah[mt][s], bl, acc[mt], 0, 0, 0);
            }
        }
        #pragma unroll
        for (int mt = 0; mt < 4; ++mt)
            #pragma unroll
            for (int r = 0; r < 4; ++r)
                part[mt][r] = fmaf(fmaxf(acc[mt][r] + b1v[t], 0.0f), w2v[t], part[mt][r]);
    }

    // ---- reduce over the 16 hidden-cols held by the quad's 16 lanes ----
    #pragma unroll
    for (int w = 1; w < 16; w <<= 1)
        #pragma unroll
        for (int mt = 0; mt < 4; ++mt)
            #pragma unroll
            for (int r = 0; r < 4; ++r)
                part[mt][r] += __shfl_xor(part[mt][r], w, 64);

    const float bb = b2[0];
    if (nn == 0) {
        #pragma unroll
        for (int mt = 0; mt < 4; ++mt) {
            const int row = wb + mt * 16 + q * 4;   // rows q*4+reg, reg=0..3
            if (row < n) {
                float4 o4 = make_float4(part[mt][0] + bb, part[mt][1] + bb,
                                        part[mt][2] + bb, part[mt][3] + bb);
                *(float4*)&o_out[row] = o4;
            }
        }
    }
}

__global__ __launch_bounds__(64, 1)
void solve_kernel(const float* __restrict__ pos,
                  const float* __restrict__ y,
                  const int*   __restrict__ nbr,
                  const float* __restrict__ theta,
                  const float* __restrict__ o_in,
                  float* __restrict__ yd,
                  float* __restrict__ od, int n)
{
    const int i = blockIdx.x * 64 + threadIdx.x;
    if (i >= n) return;

    const float sigma_sq = theta[0];
    const float phi      = theta[1];
    const float tau      = theta[2];
    const float tau_sq   = tau * sigma_sq;

    const float L2E = 1.44269504088896340736f;
    const float c1  = -phi * L2E;                       // exp(-phi*d) = exp2(c1*d)
    const float c0  = __builtin_amdgcn_logf(sigma_sq);  // log2(sigma^2)

    int idx[MM];
    const int4* nb4 = (const int4*)(nbr + (size_t)i * MM);
    #pragma unroll
    for (int k = 0; k < MM / 4; ++k) {
        int4 v = nb4[k];
        idx[4*k] = v.x; idx[4*k+1] = v.y; idx[4*k+2] = v.z; idx[4*k+3] = v.w;
    }

    float px[21], py[21];
    const float2* pos2 = (const float2*)pos;
    #pragma unroll
    for (int j = 0; j < MM; ++j) {
        float2 p = pos2[idx[j]];
        px[j] = p.x; py[j] = p.y;
    }
    {
        float2 p = pos2[i];
        px[20] = p.x; py[20] = p.y;
    }

    const float sqrtEPS = __builtin_amdgcn_sqrtf(EPSF);
    const float diagA   = __builtin_amdgcn_exp2f(fmaf(sqrtEPS, c1, c0)) + tau_sq;

    // build bordered 21x21 covariance (upper-packed), fully unrolled
    float a[231];
    #pragma unroll
    for (int r = 0; r < 21; ++r) {
        #pragma unroll
        for (int c = r; c < 21; ++c) {
            if (r == c) {
                a[UT(r, c)] = (r == 20) ? (sigma_sq + tau) : diagA;
            } else {
                float dx = px[r] - px[c];
                float dy = py[r] - py[c];
                float d2 = fmaf(dx, dx, fmaf(dy, dy, EPSF));
                float d  = __builtin_amdgcn_sqrtf(d2);
                a[UT(r, c)] = __builtin_amdgcn_exp2f(fmaf(d, c1, c0));
            }
        }
    }

    float yv[21], ov[21];
    #pragma unroll
    for (int j = 0; j < MM; ++j) {
        yv[j] = y[idx[j]];
        ov[j] = o_in[idx[j]];
    }
    yv[20] = y[i];
    ov[20] = o_in[i];

    // ---- 20 elimination steps, LOOPED (small code -> fits I$) ----
    // pivot row copied to fixed regs via switch; masked full-triangle update.
    float pr[21], pd, pyv, pov;
    #pragma unroll 1
    for (int k = 0; k < 20; ++k) {
        switch (k) {
#define CASE(K) case K: {                                     \
            pd = a[UT(K, K)]; pyv = yv[K]; pov = ov[K];       \
            _Pragma("unroll")                                 \
            for (int c = K; c < 21; ++c) pr[c] = a[UT(K, c)]; \
        } break;
        CASE(0)  CASE(1)  CASE(2)  CASE(3)  CASE(4)
        CASE(5)  CASE(6)  CASE(7)  CASE(8)  CASE(9)
        CASE(10) CASE(11) CASE(12) CASE(13) CASE(14)
        CASE(15) CASE(16) CASE(17) CASE(18) CASE(19)
#undef CASE
        default: break;
        }
        float rp = __builtin_amdgcn_rcpf(pd);
        rp = rp * (2.0f - pd * rp);                 // Newton refine
        float m[21];
        #pragma unroll
        for (int r = 0; r < 21; ++r) {
            float mr = pr[r] * rp;
            m[r] = (r > k) ? mr : 0.0f;             // rows <= k: exact no-op
        }
        #pragma unroll
        for (int r = 0; r < 21; ++r) {
            #pragma unroll
            for (int c = r; c < 21; ++c)
                a[UT(r, c)] = fmaf(-m[r], pr[c], a[UT(r, c)]);
            yv[r] = fmaf(-m[r], pyv, yv[r]);
            ov[r] = fmaf(-m[r], pov, ov[r]);
        }
    }

    const float f = a[UT(20, 20)];                  // Schur complement == f_i
    float is = __builtin_amdgcn_rsqf(f);
    is = is * fmaf(-0.5f * f * is, is, 1.5f);
    yd[i] = yv[20] * is;
    od[i] = ov[20] * is;
}

extern "C" void kernel_launch(void* const* d_in, const int* in_sizes, int n_in,
                              void* d_out, int out_size, void* d_ws, size_t ws_size,
                              hipStream_t stream)
{
    const float* x     = (const float*)d_in[0];
    const float* pos   = (const float*)d_in[1];
    const float* y     = (const float*)d_in[2];
    const int*   nbr   = (const int*)  d_in[3];
    const float* theta = (const float*)d_in[4];
    const float* w1    = (const float*)d_in[5];
    const float* b1    = (const float*)d_in[6];
    const float* w2    = (const float*)d_in[7];
    const float* b2    = (const float*)d_in[8];

    const int n = in_sizes[2];                 // N
    float* out = (float*)d_out;
    float* yd = out;
    float* od = out + (size_t)n;
    float* oo = out + 2 * (size_t)n;

    mlp_mfma_kernel<<<(n + 255) / 256, 256, 0, stream>>>(x, w1, b1, w2, b2, oo, n);
    solve_kernel<<<(n + 63) / 64, 64, 0, stream>>>(pos, y, nbr, theta, oo, yd, od, n);
}